// Round 6
// baseline (345.677 us; speedup 1.0000x reference)
//
#include <hip/hip_runtime.h>
#include <hip/hip_cooperative_groups.h>
#include <math.h>

namespace cg = cooperative_groups;

// Problem constants (KWinners2d: B=32, H=56, W=56, C=128)
#define NROW 32
#define NPR  401408          // elements per row
#define N4   100352          // float4 per row
#define NCH  128
#define NBIN 4096
#define NBLK 16              // blocks per row
#define GRIDSZ (NROW*NBLK)   // 512 blocks, 2/CU co-resident (LDS-bound)
#define CHUNK (N4/NBLK)      // 6272 float4 per block
#define BCAP 4096            // per-block LDS candidate capacity (~1.6k expected)
#define TCAP 1024            // per-row 24-bit-prefix-match capacity (~6-50 expected)

// workspace layout (bytes)
#define OFF_H1   0
#define OFF_H2   (4*NBIN*NROW)            // 512KB each
#define OFF_TCNT (2*4*NBIN*NROW)          // 32*4
#define OFF_TIE  (OFF_TCNT + 128)         // 32*1024*8 = 256KB
#define ZWORDS   (OFF_TIE/4)              // zero h1,h2,tcnt

__device__ __forceinline__ unsigned sortkey(float f) {
    unsigned u = __float_as_uint(f);
    return (u & 0x80000000u) ? ~u : (u | 0x80000000u);
}

__global__ void k_zero(unsigned* p, int n) {
    int i = blockIdx.x * blockDim.x + threadIdx.x;
    if (i < n) p[i] = 0;
}

__global__ __launch_bounds__(256) void k_fused(
        const float* __restrict__ x, const float* __restrict__ duty,
        const float* __restrict__ bsp, const int* __restrict__ kp,
        unsigned* __restrict__ h1, unsigned* __restrict__ h2,
        unsigned* __restrict__ tcnt, uint2* __restrict__ tie,
        float* __restrict__ out)
{
    cg::grid_group grid = cg::this_grid();
    __shared__ float bfs[NCH];
    __shared__ unsigned hh[2][NBIN];   // 32KB: phase1 2-copy hist; later scratch
    __shared__ uint2 sbuf[BCAP];       // 32KB: persistent candidate list
    __shared__ unsigned psum[256];
    __shared__ unsigned sml[8];
    __shared__ unsigned scnt;

    const int tid = threadIdx.x;
    const int row = blockIdx.x >> 4;
    const int bx  = blockIdx.x & 15;

    // boost factors: exp((k/n - duty[c]) * max(bs,0)); correctly-rounded f32 exp
    if (tid < NCH) {
        float bs = fmaxf(bsp[0], 0.0f);
        float td = (float)kp[0] / (float)NPR;
        bfs[tid] = (float)exp((double)((td - duty[tid]) * bs));
    }
    for (int i = tid; i < NBIN; i += 256) { hh[0][i] = 0; hh[1][i] = 0; }
    __syncthreads();

    const float4* xr = (const float4*)(x + (size_t)row * NPR) + (size_t)bx * CHUNK;
    const int base_j = bx * CHUNK * 4;
    unsigned* myh = hh[tid & 1];   // 2-copy privatization halves same-addr collisions

    // ---- phase 1: level-1 histogram (key bits 31:20) ----
    for (int i = tid; i < CHUNK; i += 256) {
        float4 v = xr[i];
        int c = (base_j + i * 4) & (NCH - 1);
        atomicAdd(&myh[sortkey(v.x * bfs[c])     >> 20], 1u);
        atomicAdd(&myh[sortkey(v.y * bfs[c + 1]) >> 20], 1u);
        atomicAdd(&myh[sortkey(v.z * bfs[c + 2]) >> 20], 1u);
        atomicAdd(&myh[sortkey(v.w * bfs[c + 3]) >> 20], 1u);
    }
    __syncthreads();
    {
        unsigned* gh = h1 + (size_t)row * NBIN;
        for (int i = tid; i < NBIN; i += 256) {
            unsigned s = hh[0][i] + hh[1][i];
            if (s) atomicAdd(&gh[i], s);
        }
    }
    grid.sync();

    // ---- phase 2: redundant scan of h1[row] -> p1, krem1 (every block) ----
    unsigned target = (unsigned)kp[0];
    unsigned p1, krem1;
    {
        const unsigned* gh = h1 + (size_t)row * NBIN;
        for (int i = tid; i < NBIN; i += 256) hh[0][i] = gh[i];
        __syncthreads();
        unsigned s = 0;
        for (int q = 0; q < 16; ++q) s += hh[0][4095 - (tid * 16 + q)];
        psum[tid] = s;
        __syncthreads();
        if (tid == 0) { unsigned a = 0; for (int t = 0; t < 256; ++t) { unsigned v = psum[t]; psum[t] = a; a += v; } }
        __syncthreads();
        unsigned cum = psum[tid];
        for (int q = 0; q < 16; ++q) {
            int bin = 4095 - (tid * 16 + q);
            unsigned c = hh[0][bin];
            if (cum < target && cum + c >= target) { sml[0] = (unsigned)bin; sml[1] = target - cum; }
            cum += c;
        }
        __syncthreads();
        p1 = sml[0]; krem1 = sml[1];
    }

    // ---- phase 3: collect candidates into persistent LDS sbuf + level-2 hist ----
    for (int i = tid; i < NBIN; i += 256) hh[1][i] = 0;
    if (tid == 0) scnt = 0;
    __syncthreads();
    for (int i = tid; i < CHUNK; i += 256) {
        float4 v = xr[i];
        int j = base_j + i * 4;
        int c = j & (NCH - 1);
        unsigned kk[4] = { sortkey(v.x * bfs[c]),     sortkey(v.y * bfs[c + 1]),
                           sortkey(v.z * bfs[c + 2]), sortkey(v.w * bfs[c + 3]) };
#pragma unroll
        for (int t = 0; t < 4; ++t) {
            if ((kk[t] >> 20) == p1) {
                atomicAdd(&hh[1][(kk[t] >> 8) & 0xFFFu], 1u);   // h2 counts ALL matches
                unsigned pos = atomicAdd(&scnt, 1u);
                if (pos < BCAP) sbuf[pos] = make_uint2((unsigned)(j + t), kk[t]);
            }
        }
    }
    __syncthreads();
    {
        unsigned* gh = h2 + (size_t)row * NBIN;
        for (int i = tid; i < NBIN; i += 256)
            if (hh[1][i]) atomicAdd(&gh[i], hh[1][i]);
    }
    grid.sync();

    // ---- phase 4: redundant scan of h2[row] (target=krem1) -> p2, krem2 ----
    unsigned p2, krem2;
    {
        const unsigned* gh = h2 + (size_t)row * NBIN;
        for (int i = tid; i < NBIN; i += 256) hh[0][i] = gh[i];
        __syncthreads();
        unsigned s = 0;
        for (int q = 0; q < 16; ++q) s += hh[0][4095 - (tid * 16 + q)];
        psum[tid] = s;
        __syncthreads();
        if (tid == 0) { unsigned a = 0; for (int t = 0; t < 256; ++t) { unsigned v = psum[t]; psum[t] = a; a += v; } }
        __syncthreads();
        unsigned cum = psum[tid];
        for (int q = 0; q < 16; ++q) {
            int bin = 4095 - (tid * 16 + q);
            unsigned c = hh[0][bin];
            if (cum < krem1 && cum + c >= krem1) { sml[2] = (unsigned)bin; sml[3] = krem1 - cum; }
            cum += c;
        }
        __syncthreads();
        p2 = sml[2]; krem2 = sml[3];
    }

    // ---- phase 5: filter own LDS sbuf for 24-bit prefix -> global tie list ----
    unsigned pref = (p1 << 12) | p2;
    {
        unsigned m = min(scnt, (unsigned)BCAP);
        for (unsigned i = tid; i < m; i += 256) {
            if ((sbuf[i].y >> 8) == pref) {
                unsigned pos = atomicAdd(&tcnt[row], 1u);   // ~6-50 per row total
                if (pos < TCAP) tie[(size_t)row * TCAP + pos] = sbuf[i];
            }
        }
    }
    grid.sync();

    // ---- phase 6: redundant level-3 hist + exact-tie rank -> tkey, cutoff ----
    unsigned tkey, cutoff;
    {
        unsigned tm = min(tcnt[row], (unsigned)TCAP);
        const uint2* tr = tie + (size_t)row * TCAP;
        hh[0][tid] = 0;    // 256 bins (bits 7:0)
        __syncthreads();
        for (unsigned i = tid; i < tm; i += 256)
            atomicAdd(&hh[0][tr[i].y & 0xFFu], 1u);
        __syncthreads();
        if (tid == 0) {
            unsigned cum = 0;
            for (int b = 255; b >= 0; --b) {
                unsigned c = hh[0][b];
                if (cum < krem2 && cum + c >= krem2) { sml[4] = (unsigned)b; sml[5] = krem2 - cum; break; }
                cum += c;
            }
            sml[6] = 0;
        }
        __syncthreads();
        unsigned q3 = sml[5];
        tkey = (pref << 8) | sml[4];
        for (unsigned i = tid; i < tm; i += 256) {
            if (tr[i].y == tkey) {
                unsigned pos = atomicAdd(&sml[6], 1u);
                if (pos < 256) psum[pos] = tr[i].x;
            }
        }
        __syncthreads();
        unsigned t = min(sml[6], 256u);
        // q3-th smallest index among exact-key ties (top_k tie-break: lower idx)
        for (unsigned i = tid; i < t; i += 256) {
            unsigned mine = psum[i], r = 0;
            for (unsigned j2 = 0; j2 < t; ++j2) r += (psum[j2] < mine) ? 1u : 0u;
            if (r == q3 - 1) sml[7] = mine;
        }
        __syncthreads();
        cutoff = sml[7];
    }

    // ---- phase 7: mask (out = winner ? x : 0) ----
    float4* outr = (float4*)(out + (size_t)row * NPR) + (size_t)bx * CHUNK;
    for (int i = tid; i < CHUNK; i += 256) {
        float4 v = xr[i];
        int j = base_j + i * 4;
        int c = j & (NCH - 1);
        unsigned k0 = sortkey(v.x * bfs[c]);
        unsigned k1 = sortkey(v.y * bfs[c + 1]);
        unsigned k2 = sortkey(v.z * bfs[c + 2]);
        unsigned k3 = sortkey(v.w * bfs[c + 3]);
        float4 o;
        o.x = (k0 > tkey || (k0 == tkey && (unsigned)(j + 0) <= cutoff)) ? v.x : 0.0f;
        o.y = (k1 > tkey || (k1 == tkey && (unsigned)(j + 1) <= cutoff)) ? v.y : 0.0f;
        o.z = (k2 > tkey || (k2 == tkey && (unsigned)(j + 2) <= cutoff)) ? v.z : 0.0f;
        o.w = (k3 > tkey || (k3 == tkey && (unsigned)(j + 3) <= cutoff)) ? v.w : 0.0f;
        outr[i] = o;
    }
}

extern "C" void kernel_launch(void* const* d_in, const int* in_sizes, int n_in,
                              void* d_out, int out_size, void* d_ws, size_t ws_size,
                              hipStream_t stream) {
    const float* x    = (const float*)d_in[0];
    const float* duty = (const float*)d_in[1];
    const float* bsp  = (const float*)d_in[2];
    const int*   kp   = (const int*)d_in[3];
    float* out = (float*)d_out;

    char* ws = (char*)d_ws;
    unsigned* h1   = (unsigned*)(ws + OFF_H1);
    unsigned* h2   = (unsigned*)(ws + OFF_H2);
    unsigned* tcnt = (unsigned*)(ws + OFF_TCNT);
    uint2*    tie  = (uint2*)(ws + OFF_TIE);

    k_zero<<<(ZWORDS + 255) / 256, 256, 0, stream>>>(h1, ZWORDS);

    void* args[] = { (void*)&x, (void*)&duty, (void*)&bsp, (void*)&kp,
                     (void*)&h1, (void*)&h2, (void*)&tcnt, (void*)&tie, (void*)&out };
    hipLaunchCooperativeKernel((const void*)k_fused, dim3(GRIDSZ), dim3(256),
                               args, 0, stream);
}

// Round 9
// 145.884 us; speedup vs baseline: 2.3695x; 2.3695x over previous
//
#include <hip/hip_runtime.h>
#include <math.h>

// KWinners2d: B=32, H=56, W=56, C=128; k=40141 (10%)
#define NROW 32
#define NPR  401408
#define N4   100352
#define NCH  128
#define NBIN 4096
#define NBLK 64                  // blocks per row
#define GRID (NROW*NBLK)         // 2048 blocks = 8 per CU
#define CHUNK (N4/NBLK)          // 1568 float4 per block
#define SCAP 1024                // global slice capacity (avg ~440 cand/block)
#define LCAP 1024                // LDS stage capacity
#define TCAP 1024

// workspace layout (bytes)
#define OFF_BF    0                         // 128 f32
#define OFF_ST    512                       // 32 * {krem2, pref}
#define OFF_TCNT  1024                      // 32 u32
#define OFF_BCNT  2048                      // 2048 u32 = 8KB
#define OFF_H1    16384                     // 512KB
#define OFF_H2    (OFF_H1 + 4*NBIN*NROW)
#define OFF_TIE   (OFF_H2 + 4*NBIN*NROW)    // 32*1024*8 = 256KB
#define OFF_EQ    (OFF_TIE + 8*TCAP*NROW)   // 2048*1024*8 = 16MB
#define ZSTART    OFF_TCNT
#define ZWORDS    ((OFF_TIE - OFF_TCNT)/4)

__device__ __forceinline__ unsigned sortkey(float f) {
    unsigned u = __float_as_uint(f);
    return (u & 0x80000000u) ? ~u : (u | 0x80000000u);
}

// parallel reverse (descending-bin) prefix scan over 4096-bin hist in global.
// Finds bin s.t. cumulative-from-top crosses `target`; writes {bin, rem} to outv.
__device__ __forceinline__ void rscan(const unsigned* __restrict__ gh, unsigned target,
                                      volatile unsigned* warr, volatile unsigned* outv) {
    int tid = threadIdx.x, lane = tid & 63, w = tid >> 6;
    unsigned hv[16], s = 0;
    int p0 = tid * 16;
#pragma unroll
    for (int q = 0; q < 16; ++q) { unsigned c = gh[4095 - (p0 + q)]; hv[q] = c; s += c; }
    unsigned inc = s;
#pragma unroll
    for (int d = 1; d < 64; d <<= 1) { unsigned o = __shfl_up(inc, d, 64); if (lane >= d) inc += o; }
    if (lane == 63) warr[w] = inc;
    __syncthreads();
    unsigned cum = inc - s;
    for (int ww = 0; ww < w; ++ww) cum += warr[ww];
#pragma unroll
    for (int q = 0; q < 16; ++q) {
        unsigned c = hv[q];
        if (cum < target && cum + c >= target) { outv[0] = (unsigned)(4095 - (p0 + q)); outv[1] = target - cum; }
        cum += c;
    }
    __syncthreads();
}

// zero hists/counters; block 0 computes boost factors (correctly-rounded f32 exp)
__global__ void k_prep(unsigned* z, int nwords, const float* duty, const float* bsp,
                       const int* kp, float* bf) {
    int i = blockIdx.x * 256 + threadIdx.x;
    if (i < nwords) z[i] = 0;
    if (blockIdx.x == 0 && threadIdx.x < NCH) {
        float bs = fmaxf(bsp[0], 0.0f);
        float td = (float)kp[0] / (float)NPR;
        bf[threadIdx.x] = (float)exp((double)((td - duty[threadIdx.x]) * bs));
    }
}

__global__ __launch_bounds__(256, 8) void k_hist(const float* __restrict__ x,
                                                 const float* __restrict__ bf,
                                                 unsigned* __restrict__ h1) {
    __shared__ unsigned h[NBIN];
    __shared__ float bfs[NCH];
    int tid = threadIdx.x;
    for (int i = tid; i < NBIN; i += 256) h[i] = 0;
    if (tid < NCH) bfs[tid] = bf[tid];
    __syncthreads();
    int row = blockIdx.x >> 6, bx = blockIdx.x & 63;
    const float4* xr = (const float4*)(x + (size_t)row * NPR) + (size_t)bx * CHUNK;
    int base = bx * CHUNK * 4;
    for (int i = tid; i < CHUNK; i += 256) {
        float4 v = xr[i];
        int c = (base + i * 4) & (NCH - 1);
        atomicAdd(&h[sortkey(v.x * bfs[c])     >> 20], 1u);
        atomicAdd(&h[sortkey(v.y * bfs[c + 1]) >> 20], 1u);
        atomicAdd(&h[sortkey(v.z * bfs[c + 2]) >> 20], 1u);
        atomicAdd(&h[sortkey(v.w * bfs[c + 3]) >> 20], 1u);
    }
    __syncthreads();
    unsigned* gh = h1 + (size_t)row * NBIN;
    for (int i = tid; i < NBIN; i += 256) {
        unsigned s = h[i];
        if (s) atomicAdd(&gh[i], s);    // ~300 nonzero bins/block
    }
}

__global__ __launch_bounds__(256, 4) void k_collect(const float* __restrict__ x,
                                                    const float* __restrict__ bf,
                                                    const int* __restrict__ kp,
                                                    const unsigned* __restrict__ h1,
                                                    unsigned* __restrict__ h2,
                                                    unsigned* __restrict__ bcnt,
                                                    uint2* __restrict__ eq) {
    __shared__ float bfs[NCH];
    __shared__ unsigned h[NBIN];
    __shared__ uint2 stage[LCAP];
    __shared__ unsigned warr[4];
    __shared__ unsigned outv[2];
    __shared__ unsigned scnt;
    int tid = threadIdx.x;
    if (tid < NCH) bfs[tid] = bf[tid];
    for (int i = tid; i < NBIN; i += 256) h[i] = 0;
    if (tid == 0) scnt = 0;
    int row = blockIdx.x >> 6, bx = blockIdx.x & 63;
    __syncthreads();
    rscan(h1 + (size_t)row * NBIN, (unsigned)kp[0], warr, outv);   // redundant per block
    unsigned p1 = outv[0];

    const float4* xr = (const float4*)(x + (size_t)row * NPR) + (size_t)bx * CHUNK;
    int base = bx * CHUNK * 4;
    uint2* slice = eq + (size_t)blockIdx.x * SCAP;
    for (int i = tid; i < CHUNK; i += 256) {
        float4 v = xr[i];
        int j = base + i * 4;
        int c = j & (NCH - 1);
        unsigned kk[4] = { sortkey(v.x * bfs[c]),     sortkey(v.y * bfs[c + 1]),
                           sortkey(v.z * bfs[c + 2]), sortkey(v.w * bfs[c + 3]) };
#pragma unroll
        for (int t = 0; t < 4; ++t) {
            if ((kk[t] >> 20) == p1) {
                atomicAdd(&h[(kk[t] >> 8) & 0xFFFu], 1u);
                unsigned pos = atomicAdd(&scnt, 1u);
                uint2 e = make_uint2((unsigned)(j + t), kk[t]);
                if (pos < LCAP) stage[pos] = e;
                else if (pos < SCAP) slice[pos] = e;
            }
        }
    }
    __syncthreads();
    unsigned m = min(scnt, (unsigned)LCAP);
    for (unsigned i = tid; i < m; i += 256) slice[i] = stage[i];
    if (tid == 0) bcnt[blockIdx.x] = min(scnt, (unsigned)SCAP);
    unsigned* gh = h2 + (size_t)row * NBIN;
    for (int i = tid; i < NBIN; i += 256)
        if (h[i]) atomicAdd(&gh[i], h[i]);
}

__global__ __launch_bounds__(256, 4) void k_selectA(const unsigned* __restrict__ h1,
                                                    const unsigned* __restrict__ h2,
                                                    const int* __restrict__ kp,
                                                    const unsigned* __restrict__ bcnt,
                                                    const uint2* __restrict__ eq,
                                                    unsigned* __restrict__ stout,
                                                    unsigned* __restrict__ tcnt,
                                                    uint2* __restrict__ tie) {
    __shared__ unsigned warr[4];
    __shared__ unsigned outv[2];
    int tid = threadIdx.x;
    int row = blockIdx.x >> 6;
    rscan(h1 + (size_t)row * NBIN, (unsigned)kp[0], warr, outv);
    unsigned p1 = outv[0], krem1 = outv[1];
    __syncthreads();
    rscan(h2 + (size_t)row * NBIN, krem1, warr, outv);
    unsigned p2 = outv[0], krem2 = outv[1];
    unsigned pref = (p1 << 12) | p2;
    if (tid == 0) { stout[row * 2] = krem2; stout[row * 2 + 1] = pref; }  // same value from all blocks
    unsigned m = bcnt[blockIdx.x];
    const uint2* sl = eq + (size_t)blockIdx.x * SCAP;
    for (unsigned i = tid; i < m; i += 256) {
        uint2 e = sl[i];
        if ((e.y >> 8) == pref) {
            unsigned pos = atomicAdd(&tcnt[row], 1u);
            if (pos < TCAP) tie[(size_t)row * TCAP + pos] = e;
        }
    }
}

__global__ __launch_bounds__(256, 8) void k_mask(const float* __restrict__ x,
                                                 const float* __restrict__ bf,
                                                 const unsigned* __restrict__ stout,
                                                 const unsigned* __restrict__ tcnt,
                                                 const uint2* __restrict__ tie,
                                                 float* __restrict__ out) {
    __shared__ float bfs[NCH];
    __shared__ uint2 stie[TCAP];
    __shared__ unsigned res[2];
    int tid = threadIdx.x;
    int row = blockIdx.x >> 6, bx = blockIdx.x & 63;
    if (tid < NCH) bfs[tid] = bf[tid];
    unsigned krem2 = stout[row * 2];
    unsigned tm = min(tcnt[row], (unsigned)TCAP);
    for (unsigned i = tid; i < tm; i += 256) stie[i] = tie[(size_t)row * TCAP + i];
    __syncthreads();
    // redundant tie-rank: winner boundary = rank krem2-1 in (key desc, idx asc)
    for (unsigned i = tid; i < tm; i += 256) {
        uint2 e = stie[i];
        unsigned r = 0;
        for (unsigned j = 0; j < tm; ++j) {
            uint2 f = stie[j];
            r += (f.y > e.y) || (f.y == e.y && f.x < e.x);
        }
        if (r == krem2 - 1) { res[0] = e.y; res[1] = e.x; }
    }
    __syncthreads();
    unsigned tkey = res[0], cutoff = res[1];

    const float4* xr = (const float4*)(x + (size_t)row * NPR) + (size_t)bx * CHUNK;
    float4* outr = (float4*)(out + (size_t)row * NPR) + (size_t)bx * CHUNK;
    int base = bx * CHUNK * 4;
    for (int i = tid; i < CHUNK; i += 256) {
        float4 v = xr[i];
        int j = base + i * 4;
        int c = j & (NCH - 1);
        unsigned k0 = sortkey(v.x * bfs[c]);
        unsigned k1 = sortkey(v.y * bfs[c + 1]);
        unsigned k2 = sortkey(v.z * bfs[c + 2]);
        unsigned k3 = sortkey(v.w * bfs[c + 3]);
        float4 o;
        o.x = (k0 > tkey || (k0 == tkey && (unsigned)(j + 0) <= cutoff)) ? v.x : 0.0f;
        o.y = (k1 > tkey || (k1 == tkey && (unsigned)(j + 1) <= cutoff)) ? v.y : 0.0f;
        o.z = (k2 > tkey || (k2 == tkey && (unsigned)(j + 2) <= cutoff)) ? v.z : 0.0f;
        o.w = (k3 > tkey || (k3 == tkey && (unsigned)(j + 3) <= cutoff)) ? v.w : 0.0f;
        outr[i] = o;
    }
}

extern "C" void kernel_launch(void* const* d_in, const int* in_sizes, int n_in,
                              void* d_out, int out_size, void* d_ws, size_t ws_size,
                              hipStream_t stream) {
    const float* x    = (const float*)d_in[0];
    const float* duty = (const float*)d_in[1];
    const float* bsp  = (const float*)d_in[2];
    const int*   kp   = (const int*)d_in[3];
    float* out = (float*)d_out;

    char* ws = (char*)d_ws;
    float*    bf   = (float*)(ws + OFF_BF);
    unsigned* st   = (unsigned*)(ws + OFF_ST);
    unsigned* tcnt = (unsigned*)(ws + OFF_TCNT);
    unsigned* bcnt = (unsigned*)(ws + OFF_BCNT);
    unsigned* h1   = (unsigned*)(ws + OFF_H1);
    unsigned* h2   = (unsigned*)(ws + OFF_H2);
    uint2*    tie  = (uint2*)(ws + OFF_TIE);
    uint2*    eq   = (uint2*)(ws + OFF_EQ);

    k_prep<<<(ZWORDS + 255) / 256, 256, 0, stream>>>((unsigned*)(ws + ZSTART), ZWORDS,
                                                     duty, bsp, kp, bf);
    k_hist<<<GRID, 256, 0, stream>>>(x, bf, h1);
    k_collect<<<GRID, 256, 0, stream>>>(x, bf, kp, h1, h2, bcnt, eq);
    k_selectA<<<GRID, 256, 0, stream>>>(h1, h2, kp, bcnt, eq, st, tcnt, tie);
    k_mask<<<GRID, 256, 0, stream>>>(x, bf, st, tcnt, tie, out);
}

// Round 10
// 144.795 us; speedup vs baseline: 2.3874x; 1.0075x over previous
//
#include <hip/hip_runtime.h>
#include <math.h>

// KWinners2d: B=32, H=56, W=56, C=128; k=40141 (10%)
#define NROW 32
#define NPR  401408
#define N4   100352
#define NCH  128
#define NBIN 4096
#define NBLK 56                  // blocks per row
#define GRID (NROW*NBLK)         // 1792 blocks = 7 per CU
#define CHUNK (N4/NBLK)          // 1792 float4 per block = 7 iters/thread exactly
#define SCAP 1024                // global slice capacity (avg ~500 cand/block)
#define LCAP 1024                // LDS stage capacity
#define TCAP 1024

// workspace layout (bytes)
#define OFF_BF    0                         // 128 f32
#define OFF_ST    512                       // (unused spare)
#define OFF_TCNT  1024                      // 32 u32
#define OFF_BCNT  2048                      // 2048 u32 = 8KB
#define OFF_H1    16384                     // 512KB
#define OFF_H2    (OFF_H1 + 4*NBIN*NROW)
#define OFF_TIE   (OFF_H2 + 4*NBIN*NROW)    // 32*1024*8 = 256KB
#define OFF_EQ    (OFF_TIE + 8*TCAP*NROW)   // 1792*1024*8 = 14.7MB
#define ZSTART    OFF_TCNT
#define ZWORDS    ((OFF_TIE - OFF_TCNT)/4)

__device__ __forceinline__ unsigned sortkey(float f) {
    unsigned u = __float_as_uint(f);
    return (u & 0x80000000u) ? ~u : (u | 0x80000000u);
}

// parallel reverse (descending-bin) prefix scan over 4096-bin hist in global.
// Finds bin s.t. cumulative-from-top crosses `target`; writes {bin, rem} to outv.
__device__ __forceinline__ void rscan(const unsigned* __restrict__ gh, unsigned target,
                                      volatile unsigned* warr, volatile unsigned* outv) {
    int tid = threadIdx.x, lane = tid & 63, w = tid >> 6;
    unsigned hv[16], s = 0;
    int p0 = tid * 16;
#pragma unroll
    for (int q = 0; q < 16; ++q) { unsigned c = gh[4095 - (p0 + q)]; hv[q] = c; s += c; }
    unsigned inc = s;
#pragma unroll
    for (int d = 1; d < 64; d <<= 1) { unsigned o = __shfl_up(inc, d, 64); if (lane >= d) inc += o; }
    if (lane == 63) warr[w] = inc;
    __syncthreads();
    unsigned cum = inc - s;
    for (int ww = 0; ww < w; ++ww) cum += warr[ww];
#pragma unroll
    for (int q = 0; q < 16; ++q) {
        unsigned c = hv[q];
        if (cum < target && cum + c >= target) { outv[0] = (unsigned)(4095 - (p0 + q)); outv[1] = target - cum; }
        cum += c;
    }
    __syncthreads();
}

// zero hists/counters; block 0 computes boost factors (correctly-rounded f32 exp)
__global__ void k_prep(unsigned* z, int nwords, const float* duty, const float* bsp,
                       const int* kp, float* bf) {
    int i = blockIdx.x * 256 + threadIdx.x;
    if (i < nwords) z[i] = 0;
    if (blockIdx.x == 0 && threadIdx.x < NCH) {
        float bs = fmaxf(bsp[0], 0.0f);
        float td = (float)kp[0] / (float)NPR;
        bf[threadIdx.x] = (float)exp((double)((td - duty[threadIdx.x]) * bs));
    }
}

// level-1 hist; packed u16 pairs in LDS (per-block per-bin <= 7168 < 32768)
__global__ __launch_bounds__(256, 8) void k_hist(const float* __restrict__ x,
                                                 const float* __restrict__ bf,
                                                 unsigned* __restrict__ h1) {
    __shared__ unsigned hp[NBIN / 2];   // 8KB
    __shared__ float bfs[NCH];
    int tid = threadIdx.x;
    for (int i = tid; i < NBIN / 2; i += 256) hp[i] = 0;
    if (tid < NCH) bfs[tid] = bf[tid];
    __syncthreads();
    int row = blockIdx.x / NBLK, bx = blockIdx.x % NBLK;
    const float4* xr = (const float4*)(x + (size_t)row * NPR) + (size_t)bx * CHUNK;
    int base = bx * CHUNK * 4;
    int c = (base + tid * 4) & (NCH - 1);   // invariant: 256*4 % 128 == 0
    float b0 = bfs[c], b1 = bfs[c + 1], b2 = bfs[c + 2], b3 = bfs[c + 3];
#pragma unroll
    for (int m = 0; m < CHUNK / 256; ++m) {
        float4 v = xr[tid + m * 256];
        unsigned k0 = sortkey(v.x * b0) >> 20;
        unsigned k1 = sortkey(v.y * b1) >> 20;
        unsigned k2 = sortkey(v.z * b2) >> 20;
        unsigned k3 = sortkey(v.w * b3) >> 20;
        atomicAdd(&hp[k0 >> 1], 1u << ((k0 & 1) << 4));
        atomicAdd(&hp[k1 >> 1], 1u << ((k1 & 1) << 4));
        atomicAdd(&hp[k2 >> 1], 1u << ((k2 & 1) << 4));
        atomicAdd(&hp[k3 >> 1], 1u << ((k3 & 1) << 4));
    }
    __syncthreads();
    unsigned* gh = h1 + (size_t)row * NBIN;
    for (int i = tid; i < NBIN / 2; i += 256) {
        unsigned p = hp[i];
        if (p & 0xFFFFu) atomicAdd(&gh[2 * i], p & 0xFFFFu);
        if (p >> 16)     atomicAdd(&gh[2 * i + 1], p >> 16);
    }
}

__global__ __launch_bounds__(256, 6) void k_collect(const float* __restrict__ x,
                                                    const float* __restrict__ bf,
                                                    const int* __restrict__ kp,
                                                    const unsigned* __restrict__ h1,
                                                    unsigned* __restrict__ h2,
                                                    unsigned* __restrict__ bcnt,
                                                    uint2* __restrict__ eq) {
    __shared__ float bfs[NCH];
    __shared__ unsigned hp[NBIN / 2];   // 8KB packed level-2 hist
    __shared__ uint2 stage[LCAP];       // 8KB
    __shared__ unsigned warr[4];
    __shared__ unsigned outv[2];
    __shared__ unsigned scnt;
    int tid = threadIdx.x;
    if (tid < NCH) bfs[tid] = bf[tid];
    for (int i = tid; i < NBIN / 2; i += 256) hp[i] = 0;
    if (tid == 0) scnt = 0;
    int row = blockIdx.x / NBLK, bx = blockIdx.x % NBLK;
    __syncthreads();
    rscan(h1 + (size_t)row * NBIN, (unsigned)kp[0], warr, outv);   // redundant per block
    unsigned p1 = outv[0];

    const float4* xr = (const float4*)(x + (size_t)row * NPR) + (size_t)bx * CHUNK;
    int base = bx * CHUNK * 4;
    uint2* slice = eq + (size_t)blockIdx.x * SCAP;
    int cch = (base + tid * 4) & (NCH - 1);
    float b0 = bfs[cch], b1 = bfs[cch + 1], b2 = bfs[cch + 2], b3 = bfs[cch + 3];
#pragma unroll
    for (int m = 0; m < CHUNK / 256; ++m) {
        float4 v = xr[tid + m * 256];
        int j = base + (tid + m * 256) * 4;
        unsigned kk[4] = { sortkey(v.x * b0), sortkey(v.y * b1),
                           sortkey(v.z * b2), sortkey(v.w * b3) };
#pragma unroll
        for (int t = 0; t < 4; ++t) {
            if ((kk[t] >> 20) == p1) {
                unsigned b2i = (kk[t] >> 8) & 0xFFFu;
                atomicAdd(&hp[b2i >> 1], 1u << ((b2i & 1) << 4));
                unsigned pos = atomicAdd(&scnt, 1u);
                uint2 e = make_uint2((unsigned)(j + t), kk[t]);
                if (pos < LCAP) stage[pos] = e;
                else if (pos < SCAP) slice[pos] = e;
            }
        }
    }
    __syncthreads();
    unsigned m2 = min(scnt, (unsigned)LCAP);
    for (unsigned i = tid; i < m2; i += 256) slice[i] = stage[i];
    if (tid == 0) bcnt[blockIdx.x] = min(scnt, (unsigned)SCAP);
    unsigned* gh = h2 + (size_t)row * NBIN;
    for (int i = tid; i < NBIN / 2; i += 256) {
        unsigned p = hp[i];
        if (p & 0xFFFFu) atomicAdd(&gh[2 * i], p & 0xFFFFu);
        if (p >> 16)     atomicAdd(&gh[2 * i + 1], p >> 16);
    }
}

__global__ __launch_bounds__(256, 4) void k_selectA(const unsigned* __restrict__ h1,
                                                    const unsigned* __restrict__ h2,
                                                    const int* __restrict__ kp,
                                                    const unsigned* __restrict__ bcnt,
                                                    const uint2* __restrict__ eq,
                                                    unsigned* __restrict__ tcnt,
                                                    uint2* __restrict__ tie) {
    __shared__ unsigned warr[4];
    __shared__ unsigned outv[2];
    int tid = threadIdx.x;
    int row = blockIdx.x / NBLK;
    rscan(h1 + (size_t)row * NBIN, (unsigned)kp[0], warr, outv);
    unsigned p1 = outv[0], krem1 = outv[1];
    __syncthreads();
    rscan(h2 + (size_t)row * NBIN, krem1, warr, outv);
    unsigned p2 = outv[0];
    unsigned pref = (p1 << 12) | p2;
    unsigned m = bcnt[blockIdx.x];
    const uint2* sl = eq + (size_t)blockIdx.x * SCAP;
    for (unsigned i = tid; i < m; i += 256) {
        uint2 e = sl[i];
        if ((e.y >> 8) == pref) {
            unsigned pos = atomicAdd(&tcnt[row], 1u);
            if (pos < TCAP) tie[(size_t)row * TCAP + pos] = e;
        }
    }
}

__global__ __launch_bounds__(256, 8) void k_mask(const float* __restrict__ x,
                                                 const float* __restrict__ bf,
                                                 const int* __restrict__ kp,
                                                 const unsigned* __restrict__ h1,
                                                 const unsigned* __restrict__ h2,
                                                 const unsigned* __restrict__ tcnt,
                                                 const uint2* __restrict__ tie,
                                                 float* __restrict__ out) {
    __shared__ float bfs[NCH];
    __shared__ uint2 stie[TCAP];        // 8KB
    __shared__ unsigned warr[4];
    __shared__ unsigned outv[2];
    __shared__ unsigned res[2];
    int tid = threadIdx.x;
    int row = blockIdx.x / NBLK, bx = blockIdx.x % NBLK;
    if (tid < NCH) bfs[tid] = bf[tid];
    __syncthreads();
    rscan(h1 + (size_t)row * NBIN, (unsigned)kp[0], warr, outv);
    unsigned p1 = outv[0], krem1 = outv[1];
    __syncthreads();
    rscan(h2 + (size_t)row * NBIN, krem1, warr, outv);
    unsigned p2 = outv[0], krem2 = outv[1];
    unsigned pref = (p1 << 12) | p2;
    unsigned tm = min(tcnt[row], (unsigned)TCAP);
    for (unsigned i = tid; i < tm; i += 256) stie[i] = tie[(size_t)row * TCAP + i];
    __syncthreads();
    // redundant tie-rank: winner boundary = rank krem2-1 in (key desc, idx asc)
    for (unsigned i = tid; i < tm; i += 256) {
        uint2 e = stie[i];
        unsigned r = 0;
        for (unsigned j = 0; j < tm; ++j) {
            uint2 f = stie[j];
            r += (f.y > e.y) || (f.y == e.y && f.x < e.x);
        }
        if (r == krem2 - 1) { res[0] = e.y; res[1] = e.x; }
    }
    __syncthreads();
    unsigned tkey = res[0], cutoff = res[1];
    (void)pref;

    const float4* xr = (const float4*)(x + (size_t)row * NPR) + (size_t)bx * CHUNK;
    float4* outr = (float4*)(out + (size_t)row * NPR) + (size_t)bx * CHUNK;
    int base = bx * CHUNK * 4;
    int cch = (base + tid * 4) & (NCH - 1);
    float b0 = bfs[cch], b1 = bfs[cch + 1], b2 = bfs[cch + 2], b3 = bfs[cch + 3];
#pragma unroll
    for (int m = 0; m < CHUNK / 256; ++m) {
        float4 v = xr[tid + m * 256];
        int j = base + (tid + m * 256) * 4;
        unsigned k0 = sortkey(v.x * b0);
        unsigned k1 = sortkey(v.y * b1);
        unsigned k2 = sortkey(v.z * b2);
        unsigned k3 = sortkey(v.w * b3);
        float4 o;
        o.x = (k0 > tkey || (k0 == tkey && (unsigned)(j + 0) <= cutoff)) ? v.x : 0.0f;
        o.y = (k1 > tkey || (k1 == tkey && (unsigned)(j + 1) <= cutoff)) ? v.y : 0.0f;
        o.z = (k2 > tkey || (k2 == tkey && (unsigned)(j + 2) <= cutoff)) ? v.z : 0.0f;
        o.w = (k3 > tkey || (k3 == tkey && (unsigned)(j + 3) <= cutoff)) ? v.w : 0.0f;
        outr[tid + m * 256] = o;
    }
}

extern "C" void kernel_launch(void* const* d_in, const int* in_sizes, int n_in,
                              void* d_out, int out_size, void* d_ws, size_t ws_size,
                              hipStream_t stream) {
    const float* x    = (const float*)d_in[0];
    const float* duty = (const float*)d_in[1];
    const float* bsp  = (const float*)d_in[2];
    const int*   kp   = (const int*)d_in[3];
    float* out = (float*)d_out;

    char* ws = (char*)d_ws;
    float*    bf   = (float*)(ws + OFF_BF);
    unsigned* tcnt = (unsigned*)(ws + OFF_TCNT);
    unsigned* bcnt = (unsigned*)(ws + OFF_BCNT);
    unsigned* h1   = (unsigned*)(ws + OFF_H1);
    unsigned* h2   = (unsigned*)(ws + OFF_H2);
    uint2*    tie  = (uint2*)(ws + OFF_TIE);
    uint2*    eq   = (uint2*)(ws + OFF_EQ);

    k_prep<<<(ZWORDS + 255) / 256, 256, 0, stream>>>((unsigned*)(ws + ZSTART), ZWORDS,
                                                     duty, bsp, kp, bf);
    k_hist<<<GRID, 256, 0, stream>>>(x, bf, h1);
    k_collect<<<GRID, 256, 0, stream>>>(x, bf, kp, h1, h2, bcnt, eq);
    k_selectA<<<GRID, 256, 0, stream>>>(h1, h2, kp, bcnt, eq, tcnt, tie);
    k_mask<<<GRID, 256, 0, stream>>>(x, bf, kp, h1, h2, tcnt, tie, out);
}